// Round 13
// baseline (28.621 us; speedup 1.0000x reference)
//
#include <hip/hip_runtime.h>

// VectorQuantizer on MI355X — fused MFMA argmin + quantize + loss, v9.
// latents: [64, 64, 32, 32] f32, embedding: [512, 64] f32.
// d_out: quantized_st [64,64,32,32] f32 (4194304 elems) then vq_loss scalar f32.
// Math: quantized_st == embedding[argmin d2], vq_loss == 1.25 * mean((q - x)^2).
// Identity: per position, (q-x)^2 summed over d = (winning_score - 2) + ||x||^2.
//
// v9 cycle-model lesson: LDS pipe was the bottleneck (k-loop ds_reads x 16
// waves/CU + 8-way-conflicted u16 store gathers). Fix: 64 pos/wave (halves
// per-CU k-loop ds_reads), store gathers moved to global embT f32 (VMEM pipe,
// L2-hot 2KB rows), bestk via one ds_read_b64 per lane.
// Kept: LDS XOR-swizzled bf16 codebook, packed u32 argmin, batched loads,
// one f32 atomic per block, no threadfence, no nontemporal.

#define NUM_EMB 512
#define DIM 64
#define HW 1024
#define TOTAL 4194304
#define FUSED_BLOCKS 512    // 128 threads = 2 waves; 64 positions per wave

typedef __attribute__((ext_vector_type(8))) short bf16x8;
typedef __attribute__((ext_vector_type(4))) float f32x4;
typedef __attribute__((ext_vector_type(4))) unsigned short u16x4;

// d_ws layout:
//   [0, 65536)        : ushort wbf[512*64]   (bf16 bits of -2*W)
//   [65536, 67584)    : float  wwb[512]      (||w||^2 + 2.0 bias)
//   [67584, 198656)   : float  embT[64][512] (transposed embedding, f32 exact)

__device__ __forceinline__ unsigned short f32_to_bf16_rne(float f) {
    unsigned int b = __builtin_bit_cast(unsigned int, f);
    return (unsigned short)((b + 0x7FFFu + ((b >> 16) & 1u)) >> 16);
}

__device__ __forceinline__ unsigned int umin32(unsigned int a, unsigned int b) {
    return a < b ? a : b;
}

__global__ __launch_bounds__(256) void prep_kernel(
    const float* __restrict__ emb, unsigned short* __restrict__ wbf,
    float* __restrict__ wwb, float* __restrict__ embT,
    float* __restrict__ out) {
    const int t = blockIdx.x * 256 + threadIdx.x;  // 32768 threads
    if (t == 0) out[TOTAL] = 0.f;                  // loss accumulator
    if (t < NUM_EMB * DIM) {
        const float e = emb[t];
        wbf[t] = f32_to_bf16_rne(-2.0f * e);
        const int k = t >> 6, d = t & 63;
        embT[(d << 9) + k] = e;                    // transpose: embT[d][k]
    }
    if (t < NUM_EMB) {
        const float* row = emb + t * DIM;
        float s = 0.f;
#pragma unroll
        for (int i = 0; i < DIM; ++i) s = fmaf(row[i], row[i], s);
        wwb[t] = s + 2.0f;                         // +2 bias keeps packed scores positive
    }
}

// Block: 2 waves x 64 positions (4 MFMA pos-tiles per wave). Wave lane l:
// c=l&15 (position in tile), g=l>>4 (k-group / dim-block). Codebook in LDS,
// XOR-swizzled: 16B chunk ch of row k stored at chunk ch^(k&7); k-tile rows
// are it*16+c so the per-lane swizzle (g^(c&7))<<4 is loop-invariant.
// acc[r] = ||w_k||^2 + 2 - 2 x.w_k for k = it*16+g*4+r, pos = t*16+c.
// Packed argmin: u32 = (score_bits & ~511) | k; running min_u32; strict-min
// keeps the smallest k on masked-score ties (jnp.argmin tie-break).
__global__ __launch_bounds__(128) void fused_vq_kernel(
    const float* __restrict__ latents, const unsigned short* __restrict__ wbf,
    const float* __restrict__ wwb, const float* __restrict__ embT,
    float* __restrict__ out) {
    extern __shared__ char smem[];                 // 67848 B dynamic
    f32x4* wl16 = (f32x4*)smem;                    // 4096 x 16B (swizzled wbf)
    float* wwl  = (float*)(smem + 65536);          // 512 floats
    unsigned short* bestk = (unsigned short*)(smem + 67584);  // 2 x 64 u16
    float* wsum = (float*)(smem + 67840);          // 2 floats

    const int tid  = threadIdx.x;                  // 0..127
    const int wave = tid >> 6;                     // 0..1
    const int l    = tid & 63;
    const int c    = l & 15;
    const int g    = l >> 4;

    const int n0  = blockIdx.x * 128 + wave * 64;  // wave's 64 positions, same b
    const int b   = n0 >> 10;
    const int hw0 = n0 & 1023;
    const float* xbase = latents + (size_t)b * (DIM * HW) + hw0 + c;

    // ---- PHASE A: issue ALL 64 x-loads as one batch ----
    float xr[64];
#pragma unroll
    for (int t = 0; t < 4; ++t)
#pragma unroll
        for (int f = 0; f < 2; ++f)
#pragma unroll
            for (int j = 0; j < 8; ++j)
                xr[t * 16 + f * 8 + j] = xbase[(f * 32 + g * 8 + j) * HW + t * 16];

    // ---- PHASE B: stage codebook into LDS, 4 pipelined batches of 8 ----
    const f32x4* wg = (const f32x4*)wbf;           // 4096 chunks of 16B
#pragma unroll
    for (int bt = 0; bt < 4; ++bt) {
        f32x4 s[8];
#pragma unroll
        for (int r = 0; r < 8; ++r) s[r] = wg[(bt * 8 + r) * 128 + tid];
#pragma unroll
        for (int r = 0; r < 8; ++r) {
            const int idx = (bt * 8 + r) * 128 + tid;
            const int sw  = (idx & ~7) | ((idx ^ (idx >> 3)) & 7);  // ch ^ (row&7)
            wl16[sw] = s[r];
        }
    }
    ((f32x4*)wwl)[tid] = ((const f32x4*)wwb)[tid]; // 128 chunks, 1 per thread

    // ---- PHASE C: convert x -> bf16 frags + x^2 (2 chains) ----
    float x2a = 0.f, x2b = 0.f;
    bf16x8 xf[4][2];
#pragma unroll
    for (int t = 0; t < 4; ++t)
#pragma unroll
        for (int f = 0; f < 2; ++f) {
            bf16x8 v;
#pragma unroll
            for (int j = 0; j < 8; ++j) {
                const float xv = xr[t * 16 + f * 8 + j];
                if (j & 1) x2a = fmaf(xv, xv, x2a);
                else       x2b = fmaf(xv, xv, x2b);
                v[j] = (short)f32_to_bf16_rne(xv);
            }
            xf[t][f] = v;
        }
    const float x2 = x2a + x2b;
    __syncthreads();                               // LDS codebook ready

    // ---- MFMA argmin over 512 codes from LDS (4 pos-tiles/wave) ----
    const int   sw0  = (g ^ (c & 7)) << 4;         // loop-invariant swizzle
    const char* arow = smem + c * 128;
    unsigned int best[4] = {0xFFFFFFFFu, 0xFFFFFFFFu, 0xFFFFFFFFu, 0xFFFFFFFFu};

#pragma unroll 4
    for (int it = 0; it < 32; ++it) {
        const bf16x8 a0  = *(const bf16x8*)(arow + it * 2048 + sw0);
        const bf16x8 a1  = *(const bf16x8*)(arow + it * 2048 + (sw0 ^ 64));
        const f32x4  ww4 = *(const f32x4*)(wwl + it * 16 + g * 4);

        const unsigned int kb = (unsigned int)(it * 16 + g * 4);
#pragma unroll
        for (int t = 0; t < 4; ++t) {
            f32x4 acc = __builtin_amdgcn_mfma_f32_16x16x32_bf16(a0, xf[t][0], ww4, 0, 0, 0);
            acc       = __builtin_amdgcn_mfma_f32_16x16x32_bf16(a1, xf[t][1], acc, 0, 0, 0);
            const unsigned int t0 = (__builtin_bit_cast(unsigned int, acc[0]) & 0xFFFFFE00u) | (kb + 0);
            const unsigned int t1 = (__builtin_bit_cast(unsigned int, acc[1]) & 0xFFFFFE00u) | (kb + 1);
            const unsigned int t2 = (__builtin_bit_cast(unsigned int, acc[2]) & 0xFFFFFE00u) | (kb + 2);
            const unsigned int t3 = (__builtin_bit_cast(unsigned int, acc[3]) & 0xFFFFFE00u) | (kb + 3);
            best[t] = umin32(umin32(umin32(t0, t1), umin32(t2, t3)), best[t]);
        }
    }

    // reduce over the 4 k-groups (lanes c, c+16, c+32, c+48)
#pragma unroll
    for (int t = 0; t < 4; ++t) {
        unsigned int o;
        o = __shfl_xor(best[t], 16); best[t] = umin32(best[t], o);
        o = __shfl_xor(best[t], 32); best[t] = umin32(best[t], o);
    }

    // ---- publish winning k: lane l owns pos l (= (l>>4)*16 + (l&15)) ----
    // static cndmask select of best[l>>4] (no runtime reg-array index)
    const unsigned int b01  = (l & 16) ? best[1] : best[0];
    const unsigned int b23  = (l & 16) ? best[3] : best[2];
    const unsigned int bsel = (l & 32) ? b23 : b01;
    bestk[wave * 64 + l] = (unsigned short)(bsel & 511u);

    // ---- loss partial: (score - 2) + ||x||^2, scores replicated x4 over g ----
    float ssum = 0.f;
#pragma unroll
    for (int t = 0; t < 4; ++t)
        ssum += __builtin_bit_cast(float, best[t] & 0xFFFFFE00u) - 2.0f;
    float contrib = x2 + 0.25f * ssum;
#pragma unroll
    for (int off = 32; off; off >>= 1) contrib += __shfl_xor(contrib, off, 64);
    if (l == 0) wsum[wave] = contrib;
    __syncthreads();                               // wsum + bestk visible
    if (tid == 0)
        atomicAdd(out + TOTAL, (wsum[0] + wsum[1]) * (1.25f / (float)TOTAL));

    // ---- store: gather exact f32 from embT (VMEM, L2-hot 2KB rows);
    //      per instr 4 d-rows x 16 lanes x 16B = 256B contiguous segments ----
    const u16x4 k4 = *(const u16x4*)(bestk + wave * 64 + (l & 15) * 4);
    float* obase = out + (size_t)b * (DIM * HW) + hw0 + (l & 15) * 4;
#pragma unroll
    for (int i = 0; i < 16; ++i) {
        const int d = i * 4 + (l >> 4);
        const float* er = embT + (d << 9);
        f32x4 q;
        q[0] = er[k4[0]]; q[1] = er[k4[1]]; q[2] = er[k4[2]]; q[3] = er[k4[3]];
        *(f32x4*)(obase + d * HW) = q;
    }
    // no trailing barrier: stores drain at endpgm
}

extern "C" void kernel_launch(void* const* d_in, const int* in_sizes, int n_in,
                              void* d_out, int out_size, void* d_ws, size_t ws_size,
                              hipStream_t stream) {
    const float* latents = (const float*)d_in[0];
    const float* emb     = (const float*)d_in[1];
    float* out = (float*)d_out;

    unsigned short* wbf  = (unsigned short*)d_ws;
    float*          wwb  = (float*)((char*)d_ws + 65536);
    float*          embT = (float*)((char*)d_ws + 67584);

    static bool attr_done = false;
    if (!attr_done) {
        (void)hipFuncSetAttribute((const void*)fused_vq_kernel,
                                  hipFuncAttributeMaxDynamicSharedMemorySize, 67848);
        attr_done = true;
    }

    prep_kernel<<<128, 256, 0, stream>>>(emb, wbf, wwb, embT, out);
    fused_vq_kernel<<<FUSED_BLOCKS, 128, 67848, stream>>>(latents, wbf, wwb, embT, out);
}

// Round 14
// 27.772 us; speedup vs baseline: 1.0306x; 1.0306x over previous
//
#include <hip/hip_runtime.h>

// VectorQuantizer on MI355X — v10: split-K-across-waves, W-in-registers.
// latents: [64, 64, 32, 32] f32, embedding: [512, 64] f32.
// d_out: quantized_st [64,64,32,32] f32 (4194304 elems) then vq_loss scalar f32.
// Math: quantized_st == embedding[argmin d2], vq_loss == 1.25 * mean((q - x)^2).
// Identity: per position, (q-x)^2 summed over d = (winning_score - 2) + ||x||^2.
//
// v10 structure (from v6-v9 accounting: 64KB LDS codebook pinned occupancy at
// ~8 waves/CU): codebook fragments live in REGISTERS (each wave owns 64 codes;
// 8 waves cover 512), only x (16KB swizzled bf16) in LDS; cross-wave argmin
// via LDS atomicMin on packed score|k. 17KB LDS + <=128 VGPR -> 16 waves/CU.
// Kept: packed u32 argmin (strict-min = jnp tie-break), +2 bias, batched
// loads, one f32 atomic per block, no threadfence, no nontemporal.

#define NUM_EMB 512
#define DIM 64
#define HW 1024
#define TOTAL 4194304
#define FUSED_BLOCKS 512    // 512 threads = 8 waves; 128 positions per block

typedef __attribute__((ext_vector_type(8))) short bf16x8;
typedef __attribute__((ext_vector_type(4))) float f32x4;
typedef __attribute__((ext_vector_type(4))) unsigned int u32x4;

// d_ws layout:
//   [0, 65536)        : ushort wbf[512*64]   (bf16 bits of -2*W)
//   [65536, 67584)    : float  wwb[512]      (||w||^2 + 2.0 bias)

__device__ __forceinline__ unsigned short f32_to_bf16_rne(float f) {
    unsigned int b = __builtin_bit_cast(unsigned int, f);
    return (unsigned short)((b + 0x7FFFu + ((b >> 16) & 1u)) >> 16);
}

__device__ __forceinline__ unsigned int umin32(unsigned int a, unsigned int b) {
    return a < b ? a : b;
}

__global__ __launch_bounds__(256) void prep_kernel(
    const float* __restrict__ emb, unsigned short* __restrict__ wbf,
    float* __restrict__ wwb, float* __restrict__ out) {
    const int t = blockIdx.x * 256 + threadIdx.x;  // 32768 threads
    if (t == 0) out[TOTAL] = 0.f;                  // loss accumulator
    if (t < NUM_EMB * DIM) wbf[t] = f32_to_bf16_rne(-2.0f * emb[t]);
    if (t < NUM_EMB) {
        const float* row = emb + t * DIM;
        float s = 0.f;
#pragma unroll
        for (int i = 0; i < DIM; ++i) s = fmaf(row[i], row[i], s);
        wwb[t] = s + 2.0f;                         // +2 bias keeps packed scores positive
    }
}

// Wave w owns codes [w*64, w*64+64). Lane l: c=l&15, g=l>>4.
// A-frag af[kt][f]: code kw+kt*16+c, dims f*32+g*8..+7 (16B from wbf).
// x staged in LDS as [128 pos][8 chunks of 16B], chunk ch stored at ch^(pos&7).
// B-frag for pos-tile pt: row pt*16+c, logical chunk f*4+g -> phys ^(c&7).
// MFMA D: col=lane&15=position, row=g*4+r=code-row -> acc[r] is the score of
// code kw+kt*16+g*4+r at position pt*16+c, biased: ||w||^2+2-2x.w.
// Packed argmin: u32 = (score_bits & ~511) | k; LDS atomicMin combines waves;
// strict min keeps smallest k on masked-score ties (jnp.argmin tie-break).
__global__ __launch_bounds__(512, 4) void fused_vq_kernel(
    const float* __restrict__ latents, const unsigned short* __restrict__ wbf,
    const float* __restrict__ wwb, float* __restrict__ out) {
    __shared__ char xl[16384];                     // swizzled bf16 x
    __shared__ unsigned int bestmin[128];
    __shared__ float wsum[8];

    const int tid  = threadIdx.x;
    const int wave = tid >> 6;                     // 0..7
    const int l    = tid & 63;
    const int c    = l & 15;
    const int g    = l >> 4;

    const int n0  = blockIdx.x * 128;              // 128 positions, same b row
    const int b   = n0 >> 10;
    const int hw0 = n0 & 1023;

    // ---- PHASE A: issue x-loads (16 per thread, coalesced 256B/instr) ----
    const int pos = tid & 127;                     // position this thread stages
    const int ch2 = tid >> 7;                      // dim-quarter (16 dims)
    const float* xp = latents + (size_t)b * (DIM * HW) + hw0 + pos;
    float xv[16];
#pragma unroll
    for (int j = 0; j < 16; ++j) xv[j] = xp[(ch2 * 16 + j) * HW];

    // ---- PHASE B: issue W-frag loads (regs; L2-hot; used after barrier) ----
    const int kw = wave * 64;
    bf16x8 af[4][2];
    f32x4  ww4[4];
#pragma unroll
    for (int kt = 0; kt < 4; ++kt) {
#pragma unroll
        for (int f = 0; f < 2; ++f)
            af[kt][f] = *(const bf16x8*)(wbf + (kw + kt * 16 + c) * 64 + f * 32 + g * 8);
        ww4[kt] = *(const f32x4*)(wwb + kw + kt * 16 + g * 4);
    }

    if (tid < 128) bestmin[tid] = 0xFFFFFFFFu;

    // ---- convert x -> bf16, accumulate x^2, write swizzled LDS chunks ----
    float x2a = 0.f, x2b = 0.f;
    unsigned short xb[16];
#pragma unroll
    for (int j = 0; j < 16; ++j) {
        const float v = xv[j];
        if (j & 1) x2a = fmaf(v, v, x2a); else x2b = fmaf(v, v, x2b);
        xb[j] = f32_to_bf16_rne(v);
    }
    const float x2 = x2a + x2b;
#pragma unroll
    for (int h = 0; h < 2; ++h) {
        const int ch = ch2 * 2 + h;
        const int sw = ch ^ (pos & 7);
        *(bf16x8*)(xl + pos * 128 + sw * 16) = *(const bf16x8*)(xb + h * 8);
    }
    __syncthreads();                               // x staged; W-frags arrived

    // ---- compute: 8 pos-tiles x (4 k-tiles x 2 MFMA) per wave ----
    const int swa = (g ^ (c & 7)) << 4;            // f=0 phys chunk byte
    const int swb = (((4 + g) ^ (c & 7))) << 4;    // f=1 phys chunk byte
#pragma unroll
    for (int pt = 0; pt < 8; ++pt) {
        const char* xrow = xl + (pt * 16 + c) * 128;
        const bf16x8 b0 = *(const bf16x8*)(xrow + swa);
        const bf16x8 b1 = *(const bf16x8*)(xrow + swb);
        unsigned int best = 0xFFFFFFFFu;
#pragma unroll
        for (int kt = 0; kt < 4; ++kt) {
            f32x4 acc = __builtin_amdgcn_mfma_f32_16x16x32_bf16(af[kt][0], b0, ww4[kt], 0, 0, 0);
            acc       = __builtin_amdgcn_mfma_f32_16x16x32_bf16(af[kt][1], b1, acc, 0, 0, 0);
            const unsigned int kb = (unsigned int)(kw + kt * 16 + g * 4);
            const unsigned int t0 = (__builtin_bit_cast(unsigned int, acc[0]) & 0xFFFFFE00u) | (kb + 0);
            const unsigned int t1 = (__builtin_bit_cast(unsigned int, acc[1]) & 0xFFFFFE00u) | (kb + 1);
            const unsigned int t2 = (__builtin_bit_cast(unsigned int, acc[2]) & 0xFFFFFE00u) | (kb + 2);
            const unsigned int t3 = (__builtin_bit_cast(unsigned int, acc[3]) & 0xFFFFFE00u) | (kb + 3);
            best = umin32(umin32(umin32(t0, t1), umin32(t2, t3)), best);
        }
        unsigned int o;
        o = __shfl_xor(best, 16); best = umin32(best, o);
        o = __shfl_xor(best, 32); best = umin32(best, o);
        if (l < 16) atomicMin(&bestmin[pt * 16 + c], best);
    }
    __syncthreads();                               // bestmin final across waves

    // ---- loss: x2 (all threads) + (score-2) (first 128 threads) ----
    float contrib = x2;
    if (tid < 128)
        contrib += __builtin_bit_cast(float, bestmin[tid] & 0xFFFFFE00u) - 2.0f;
#pragma unroll
    for (int off = 32; off; off >>= 1) contrib += __shfl_xor(contrib, off, 64);
    if (l == 0) wsum[wave] = contrib;
    __syncthreads();
    if (tid == 0) {
        float tot = 0.f;
#pragma unroll
        for (int i = 0; i < 8; ++i) tot += wsum[i];
        atomicAdd(out + TOTAL, tot * (1.25f / (float)TOTAL));
    }

    // ---- store: q = -0.5 * bf16(-2w) gathered from L2-hot wbf ----
    // vec v covers [d][p4..p4+3]; per wave-instr: 2 contiguous 512B segments.
    float* obase = out + (size_t)b * (DIM * HW) + hw0;
#pragma unroll
    for (int i = 0; i < 4; ++i) {
        const int v  = i * 512 + tid;              // 2048 f32x4 vecs
        const int d  = v >> 5;
        const int p4 = (v & 31) * 4;
        const u32x4 bm = *(const u32x4*)(bestmin + p4);
        f32x4 q;
#pragma unroll
        for (int j = 0; j < 4; ++j) {
            const int k = (int)(bm[j] & 511u);
            const unsigned short wv = wbf[k * 64 + d];
            q[j] = -0.5f * __builtin_bit_cast(float, (unsigned int)wv << 16);
        }
        *(f32x4*)(obase + d * HW + p4) = q;
    }
    // no trailing barrier: stores drain at endpgm
}

extern "C" void kernel_launch(void* const* d_in, const int* in_sizes, int n_in,
                              void* d_out, int out_size, void* d_ws, size_t ws_size,
                              hipStream_t stream) {
    const float* latents = (const float*)d_in[0];
    const float* emb     = (const float*)d_in[1];
    float* out = (float*)d_out;

    unsigned short* wbf = (unsigned short*)d_ws;
    float*          wwb = (float*)((char*)d_ws + 65536);

    prep_kernel<<<128, 256, 0, stream>>>(emb, wbf, wwb, out);
    fused_vq_kernel<<<FUSED_BLOCKS, 512, 0, stream>>>(latents, wbf, wwb, out);
}

// Round 15
// 25.961 us; speedup vs baseline: 1.1025x; 1.0698x over previous
//
#include <hip/hip_runtime.h>

// VectorQuantizer on MI355X — v11: v10 (split-K, W-in-regs) + line-efficient
// row-gather store.
// latents: [64, 64, 32, 32] f32, embedding: [512, 64] f32.
// d_out: quantized_st [64,64,32,32] f32 (4194304 elems) then vq_loss scalar f32.
// Math: quantized_st == embedding[argmin d2], vq_loss == 1.25 * mean((q - x)^2).
// Identity: per position, (q-x)^2 summed over d = (winning_score - 2) + ||x||^2.
//
// v11 change (single-variable vs v10): store phase gathers each winning
// codebook ROW with 2 x dwordx4 per thread (4 threads/position, d-quarter
// each) instead of 16 scalar u16 gathers — 8x fewer gather instrs, ~4x fewer
// 64B-line touches on the texture pipe. Everything else identical to v10.

#define NUM_EMB 512
#define DIM 64
#define HW 1024
#define TOTAL 4194304
#define FUSED_BLOCKS 512    // 512 threads = 8 waves; 128 positions per block

typedef __attribute__((ext_vector_type(8))) short bf16x8;
typedef __attribute__((ext_vector_type(4))) float f32x4;

// d_ws layout:
//   [0, 65536)        : ushort wbf[512*64]   (bf16 bits of -2*W)
//   [65536, 67584)    : float  wwb[512]      (||w||^2 + 2.0 bias)

__device__ __forceinline__ unsigned short f32_to_bf16_rne(float f) {
    unsigned int b = __builtin_bit_cast(unsigned int, f);
    return (unsigned short)((b + 0x7FFFu + ((b >> 16) & 1u)) >> 16);
}

__device__ __forceinline__ unsigned int umin32(unsigned int a, unsigned int b) {
    return a < b ? a : b;
}

__global__ __launch_bounds__(256) void prep_kernel(
    const float* __restrict__ emb, unsigned short* __restrict__ wbf,
    float* __restrict__ wwb, float* __restrict__ out) {
    const int t = blockIdx.x * 256 + threadIdx.x;  // 32768 threads
    if (t == 0) out[TOTAL] = 0.f;                  // loss accumulator
    if (t < NUM_EMB * DIM) wbf[t] = f32_to_bf16_rne(-2.0f * emb[t]);
    if (t < NUM_EMB) {
        const float* row = emb + t * DIM;
        float s = 0.f;
#pragma unroll
        for (int i = 0; i < DIM; ++i) s = fmaf(row[i], row[i], s);
        wwb[t] = s + 2.0f;                         // +2 bias keeps packed scores positive
    }
}

// Wave w owns codes [w*64, w*64+64). Lane l: c=l&15, g=l>>4.
// A-frag af[kt][f]: code kw+kt*16+c, dims f*32+g*8..+7 (16B from wbf).
// x staged in LDS as [128 pos][8 chunks of 16B], chunk ch stored at ch^(pos&7).
// B-frag for pos-tile pt: row pt*16+c, logical chunk f*4+g -> phys ^(c&7).
// MFMA D: col=lane&15=position, row=g*4+r=code-row -> acc[r] is the score of
// code kw+kt*16+g*4+r at position pt*16+c, biased: ||w||^2+2-2x.w.
// Packed argmin: u32 = (score_bits & ~511) | k; LDS atomicMin combines waves;
// strict min keeps smallest k on masked-score ties (jnp.argmin tie-break).
__global__ __launch_bounds__(512, 4) void fused_vq_kernel(
    const float* __restrict__ latents, const unsigned short* __restrict__ wbf,
    const float* __restrict__ wwb, float* __restrict__ out) {
    __shared__ char xl[16384];                     // swizzled bf16 x
    __shared__ unsigned int bestmin[128];
    __shared__ float wsum[8];

    const int tid  = threadIdx.x;
    const int wave = tid >> 6;                     // 0..7
    const int l    = tid & 63;
    const int c    = l & 15;
    const int g    = l >> 4;

    const int n0  = blockIdx.x * 128;              // 128 positions, same b row
    const int b   = n0 >> 10;
    const int hw0 = n0 & 1023;

    // ---- PHASE A: issue x-loads (16 per thread, coalesced 512B/instr) ----
    const int pos = tid & 127;                     // position this thread stages
    const int ch2 = tid >> 7;                      // dim-quarter (16 dims)
    const float* xp = latents + (size_t)b * (DIM * HW) + hw0 + pos;
    float xv[16];
#pragma unroll
    for (int j = 0; j < 16; ++j) xv[j] = xp[(ch2 * 16 + j) * HW];

    // ---- PHASE B: issue W-frag loads (regs; L2-hot; used after barrier) ----
    const int kw = wave * 64;
    bf16x8 af[4][2];
    f32x4  ww4[4];
#pragma unroll
    for (int kt = 0; kt < 4; ++kt) {
#pragma unroll
        for (int f = 0; f < 2; ++f)
            af[kt][f] = *(const bf16x8*)(wbf + (kw + kt * 16 + c) * 64 + f * 32 + g * 8);
        ww4[kt] = *(const f32x4*)(wwb + kw + kt * 16 + g * 4);
    }

    if (tid < 128) bestmin[tid] = 0xFFFFFFFFu;

    // ---- convert x -> bf16, accumulate x^2, write swizzled LDS chunks ----
    float x2a = 0.f, x2b = 0.f;
    unsigned short xb[16];
#pragma unroll
    for (int j = 0; j < 16; ++j) {
        const float v = xv[j];
        if (j & 1) x2a = fmaf(v, v, x2a); else x2b = fmaf(v, v, x2b);
        xb[j] = f32_to_bf16_rne(v);
    }
    const float x2 = x2a + x2b;
#pragma unroll
    for (int h = 0; h < 2; ++h) {
        const int ch = ch2 * 2 + h;
        const int sw = ch ^ (pos & 7);
        *(bf16x8*)(xl + pos * 128 + sw * 16) = *(const bf16x8*)(xb + h * 8);
    }
    __syncthreads();                               // x staged; W-frags arrived

    // ---- compute: 8 pos-tiles x (4 k-tiles x 2 MFMA) per wave ----
    const int swa = (g ^ (c & 7)) << 4;            // f=0 phys chunk byte
    const int swb = (((4 + g) ^ (c & 7))) << 4;    // f=1 phys chunk byte
#pragma unroll
    for (int pt = 0; pt < 8; ++pt) {
        const char* xrow = xl + (pt * 16 + c) * 128;
        const bf16x8 b0 = *(const bf16x8*)(xrow + swa);
        const bf16x8 b1 = *(const bf16x8*)(xrow + swb);
        unsigned int best = 0xFFFFFFFFu;
#pragma unroll
        for (int kt = 0; kt < 4; ++kt) {
            f32x4 acc = __builtin_amdgcn_mfma_f32_16x16x32_bf16(af[kt][0], b0, ww4[kt], 0, 0, 0);
            acc       = __builtin_amdgcn_mfma_f32_16x16x32_bf16(af[kt][1], b1, acc, 0, 0, 0);
            const unsigned int kb = (unsigned int)(kw + kt * 16 + g * 4);
            const unsigned int t0 = (__builtin_bit_cast(unsigned int, acc[0]) & 0xFFFFFE00u) | (kb + 0);
            const unsigned int t1 = (__builtin_bit_cast(unsigned int, acc[1]) & 0xFFFFFE00u) | (kb + 1);
            const unsigned int t2 = (__builtin_bit_cast(unsigned int, acc[2]) & 0xFFFFFE00u) | (kb + 2);
            const unsigned int t3 = (__builtin_bit_cast(unsigned int, acc[3]) & 0xFFFFFE00u) | (kb + 3);
            best = umin32(umin32(umin32(t0, t1), umin32(t2, t3)), best);
        }
        unsigned int o;
        o = __shfl_xor(best, 16); best = umin32(best, o);
        o = __shfl_xor(best, 32); best = umin32(best, o);
        if (l < 16) atomicMin(&bestmin[pt * 16 + c], best);
    }
    __syncthreads();                               // bestmin final across waves

    // ---- loss: x2 (all threads) + (score-2) (first 128 threads) ----
    float contrib = x2;
    if (tid < 128)
        contrib += __builtin_bit_cast(float, bestmin[tid] & 0xFFFFFE00u) - 2.0f;
#pragma unroll
    for (int off = 32; off; off >>= 1) contrib += __shfl_xor(contrib, off, 64);
    if (l == 0) wsum[wave] = contrib;
    __syncthreads();
    if (tid == 0) {
        float tot = 0.f;
#pragma unroll
        for (int i = 0; i < 8; ++i) tot += wsum[i];
        atomicAdd(out + TOTAL, tot * (1.25f / (float)TOTAL));
    }

    // ---- store: 4 threads per position; thread loads its d-quarter of the
    //      winning bf16 row with 2 x dwordx4 (line-efficient gather), then
    //      16 scalar stores (4 x 64B coalesced segments per wave-instr).
    //      q = -0.5 * bf16(-2w) (exact *0.5; bf16 rounding ~4e-6). ----
    const int p = tid >> 2;                        // position 0..127
    const int q = tid & 3;                         // d-quarter
    const int k = (int)(bestmin[p] & 511u);
    const bf16x8 r0 = *(const bf16x8*)(wbf + k * 64 + q * 16);
    const bf16x8 r1 = *(const bf16x8*)(wbf + k * 64 + q * 16 + 8);
    float* obase = out + (size_t)b * (DIM * HW) + hw0 + p;
#pragma unroll
    for (int j = 0; j < 8; ++j)
        obase[(q * 16 + j) * HW] =
            -0.5f * __builtin_bit_cast(float, (unsigned int)(unsigned short)r0[j] << 16);
#pragma unroll
    for (int j = 0; j < 8; ++j)
        obase[(q * 16 + 8 + j) * HW] =
            -0.5f * __builtin_bit_cast(float, (unsigned int)(unsigned short)r1[j] << 16);
    // no trailing barrier: stores drain at endpgm
}

extern "C" void kernel_launch(void* const* d_in, const int* in_sizes, int n_in,
                              void* d_out, int out_size, void* d_ws, size_t ws_size,
                              hipStream_t stream) {
    const float* latents = (const float*)d_in[0];
    const float* emb     = (const float*)d_in[1];
    float* out = (float*)d_out;

    unsigned short* wbf = (unsigned short*)d_ws;
    float*          wwb = (float*)((char*)d_ws + 65536);

    prep_kernel<<<128, 256, 0, stream>>>(emb, wbf, wwb, out);
    fused_vq_kernel<<<FUSED_BLOCKS, 512, 0, stream>>>(latents, wbf, wwb, out);
}

// Round 16
// 22.018 us; speedup vs baseline: 1.2999x; 1.1791x over previous
//
#include <hip/hip_runtime.h>

// VectorQuantizer on MI355X — v12: prep-free, atomic-free.
// latents: [64, 64, 32, 32] f32, embedding: [512, 64] f32.
// d_out: quantized_st [64,64,32,32] f32 (4194304 elems) then vq_loss scalar f32.
// Math: quantized_st == embedding[argmin d2], vq_loss == 1.25 * mean((q - x)^2).
// Identity: per position, (q-x)^2 summed over d = (winning_score - 2) + ||x||^2,
// where score = ||w||^2 + 2 - 2 x.w (the +2 bias keeps packed scores positive).
//
// v12 vs v11: no prep kernel (each wave builds its 64-code MFMA A-frags and
// ||w||^2+2 C-operand directly from raw f32 emb: bf16(-2w) == -2*bf16(w)
// exactly; row-sum via shfl reduce + 4 lane-gather shfls); store gathers
// exact f32 emb quarters (contiguous 64B per thread); loss via partial[512]
// + tiny finalize kernel — no global atomics, no cross-kernel d_ws deps.

#define NUM_EMB 512
#define DIM 64
#define HW 1024
#define TOTAL 4194304
#define FUSED_BLOCKS 512    // 512 threads = 8 waves; 128 positions per block

typedef __attribute__((ext_vector_type(8))) short bf16x8;
typedef __attribute__((ext_vector_type(4))) float f32x4;

// d_ws layout: [0, 2048) : float partial[512]

__device__ __forceinline__ unsigned short f32_to_bf16_rne(float f) {
    unsigned int b = __builtin_bit_cast(unsigned int, f);
    return (unsigned short)((b + 0x7FFFu + ((b >> 16) & 1u)) >> 16);
}

__device__ __forceinline__ unsigned int umin32(unsigned int a, unsigned int b) {
    return a < b ? a : b;
}

// Wave w owns codes [w*64, w*64+64). Lane l: c=l&15, g=l>>4.
// A-frag af[kt][f]: code kw+kt*16+c, dims f*32+g*8..+7, bf16(-2w).
// x staged in LDS as [128 pos][8 chunks of 16B], chunk ch stored at ch^(pos&7).
// B-frag for pos-tile pt: row pt*16+c, logical chunk f*4+g -> phys ^(c&7).
// MFMA D: col=lane&15=position, row=g*4+r -> acc[r] = biased score of code
// kw+kt*16+g*4+r at position pt*16+c.  Packed argmin: u32 =
// (score_bits & ~511) | k; LDS atomicMin combines waves; strict min keeps
// smallest k on masked-score ties (jnp.argmin tie-break).
__global__ __launch_bounds__(512, 4) void fused_vq_kernel(
    const float* __restrict__ latents, const float* __restrict__ emb,
    float* __restrict__ out, float* __restrict__ partial) {
    __shared__ char xl[16384];                     // swizzled bf16 x
    __shared__ unsigned int bestmin[128];
    __shared__ float wsum[8];

    const int tid  = threadIdx.x;
    const int wave = tid >> 6;                     // 0..7
    const int l    = tid & 63;
    const int c    = l & 15;
    const int g    = l >> 4;

    const int n0  = blockIdx.x * 128;              // 128 positions, same b row
    const int b   = n0 >> 10;
    const int hw0 = n0 & 1023;

    // ---- PHASE A: issue x-loads (16 per thread, coalesced) ----
    const int pos = tid & 127;                     // position this thread stages
    const int ch2 = tid >> 7;                      // dim-quarter (16 dims)
    const float* xp = latents + (size_t)b * (DIM * HW) + hw0 + pos;
    float xv[16];
#pragma unroll
    for (int j = 0; j < 16; ++j) xv[j] = xp[(ch2 * 16 + j) * HW];

    if (tid < 128) bestmin[tid] = 0xFFFFFFFFu;

    // ---- PHASE B: build W-frags from raw emb (L3/L2-hot, 16KB per wave) ----
    const int kw = wave * 64;
    bf16x8 af[4][2];
    f32x4  ww4[4];
#pragma unroll
    for (int kt = 0; kt < 4; ++kt) {
        const float* wrow = emb + (kw + kt * 16 + c) * 64;
        const f32x4 w0a = *(const f32x4*)(wrow + g * 8);
        const f32x4 w0b = *(const f32x4*)(wrow + g * 8 + 4);
        const f32x4 w1a = *(const f32x4*)(wrow + 32 + g * 8);
        const f32x4 w1b = *(const f32x4*)(wrow + 32 + g * 8 + 4);
        // per-lane partial ||w||^2 over this lane's 16 dims
        float ps = 0.f;
        bf16x8 a0, a1;
#pragma unroll
        for (int j = 0; j < 4; ++j) {
            ps = fmaf(w0a[j], w0a[j], ps);  a0[j]     = (short)f32_to_bf16_rne(-2.0f * w0a[j]);
            ps = fmaf(w0b[j], w0b[j], ps);  a0[j + 4] = (short)f32_to_bf16_rne(-2.0f * w0b[j]);
            ps = fmaf(w1a[j], w1a[j], ps);  a1[j]     = (short)f32_to_bf16_rne(-2.0f * w1a[j]);
            ps = fmaf(w1b[j], w1b[j], ps);  a1[j + 4] = (short)f32_to_bf16_rne(-2.0f * w1b[j]);
        }
        af[kt][0] = a0;
        af[kt][1] = a1;
        // full ||w(kw+kt*16+c)||^2: sum the 4 g-partials (lanes c, c+16, ...)
        float s = ps + __shfl_xor(ps, 16);
        s += __shfl_xor(s, 32);
        // C-operand layout needs codes g*4+r -> gather from lanes (g*4+r)
        f32x4 w4;
#pragma unroll
        for (int r = 0; r < 4; ++r) w4[r] = __shfl(s, g * 4 + r) + 2.0f;
        ww4[kt] = w4;
    }

    // ---- convert x -> bf16, accumulate x^2, write swizzled LDS chunks ----
    float x2a = 0.f, x2b = 0.f;
    unsigned short xb[16];
#pragma unroll
    for (int j = 0; j < 16; ++j) {
        const float v = xv[j];
        if (j & 1) x2a = fmaf(v, v, x2a); else x2b = fmaf(v, v, x2b);
        xb[j] = f32_to_bf16_rne(v);
    }
    const float x2 = x2a + x2b;
#pragma unroll
    for (int h = 0; h < 2; ++h) {
        const int ch = ch2 * 2 + h;
        const int sw = ch ^ (pos & 7);
        *(bf16x8*)(xl + pos * 128 + sw * 16) = *(const bf16x8*)(xb + h * 8);
    }
    __syncthreads();                               // x staged

    // ---- compute: 8 pos-tiles x (4 k-tiles x 2 MFMA) per wave ----
    const int swa = (g ^ (c & 7)) << 4;            // f=0 phys chunk byte
    const int swb = (((4 + g) ^ (c & 7))) << 4;    // f=1 phys chunk byte
#pragma unroll
    for (int pt = 0; pt < 8; ++pt) {
        const char* xrow = xl + (pt * 16 + c) * 128;
        const bf16x8 b0 = *(const bf16x8*)(xrow + swa);
        const bf16x8 b1 = *(const bf16x8*)(xrow + swb);
        unsigned int best = 0xFFFFFFFFu;
#pragma unroll
        for (int kt = 0; kt < 4; ++kt) {
            f32x4 acc = __builtin_amdgcn_mfma_f32_16x16x32_bf16(af[kt][0], b0, ww4[kt], 0, 0, 0);
            acc       = __builtin_amdgcn_mfma_f32_16x16x32_bf16(af[kt][1], b1, acc, 0, 0, 0);
            const unsigned int kb = (unsigned int)(kw + kt * 16 + g * 4);
            const unsigned int t0 = (__builtin_bit_cast(unsigned int, acc[0]) & 0xFFFFFE00u) | (kb + 0);
            const unsigned int t1 = (__builtin_bit_cast(unsigned int, acc[1]) & 0xFFFFFE00u) | (kb + 1);
            const unsigned int t2 = (__builtin_bit_cast(unsigned int, acc[2]) & 0xFFFFFE00u) | (kb + 2);
            const unsigned int t3 = (__builtin_bit_cast(unsigned int, acc[3]) & 0xFFFFFE00u) | (kb + 3);
            best = umin32(umin32(umin32(t0, t1), umin32(t2, t3)), best);
        }
        unsigned int o;
        o = __shfl_xor(best, 16); best = umin32(best, o);
        o = __shfl_xor(best, 32); best = umin32(best, o);
        if (l < 16) atomicMin(&bestmin[pt * 16 + c], best);
    }
    __syncthreads();                               // bestmin final across waves

    // ---- loss: x2 (all threads) + (score-2) (first 128 threads) ----
    float contrib = x2;
    if (tid < 128)
        contrib += __builtin_bit_cast(float, bestmin[tid] & 0xFFFFFE00u) - 2.0f;
#pragma unroll
    for (int off = 32; off; off >>= 1) contrib += __shfl_xor(contrib, off, 64);
    if (l == 0) wsum[wave] = contrib;
    __syncthreads();
    if (tid == 0) {
        float tot = 0.f;
#pragma unroll
        for (int i = 0; i < 8; ++i) tot += wsum[i];
        partial[blockIdx.x] = tot;                 // plain store, no atomic
    }

    // ---- store: 4 threads/position; thread reads its contiguous 64B quarter
    //      of the winning emb row (exact f32), 16 coalesced scalar stores ----
    const int p = tid >> 2;                        // position 0..127
    const int q = tid & 3;                         // d-quarter
    const int k = (int)(bestmin[p] & 511u);
    const f32x4* er = (const f32x4*)(emb + k * 64 + q * 16);
    const f32x4 q0 = er[0], q1 = er[1], q2 = er[2], q3 = er[3];
    float* obase = out + (size_t)b * (DIM * HW) + hw0 + p;
#pragma unroll
    for (int j = 0; j < 4; ++j) obase[(q * 16 + j)      * HW] = q0[j];
#pragma unroll
    for (int j = 0; j < 4; ++j) obase[(q * 16 + 4 + j)  * HW] = q1[j];
#pragma unroll
    for (int j = 0; j < 4; ++j) obase[(q * 16 + 8 + j)  * HW] = q2[j];
#pragma unroll
    for (int j = 0; j < 4; ++j) obase[(q * 16 + 12 + j) * HW] = q3[j];
    // no trailing barrier: stores drain at endpgm
}

__global__ __launch_bounds__(512) void finalize_kernel(
    const float* __restrict__ partial, float* __restrict__ out) {
    const int tid = threadIdx.x;
    double s = (double)partial[tid];
#pragma unroll
    for (int off = 32; off; off >>= 1) s += __shfl_xor(s, off, 64);
    __shared__ double dsum[8];
    if ((tid & 63) == 0) dsum[tid >> 6] = s;
    __syncthreads();
    if (tid == 0) {
        double tot = 0.0;
#pragma unroll
        for (int i = 0; i < 8; ++i) tot += dsum[i];
        out[TOTAL] = (float)(1.25 * tot / (double)TOTAL);
    }
}

extern "C" void kernel_launch(void* const* d_in, const int* in_sizes, int n_in,
                              void* d_out, int out_size, void* d_ws, size_t ws_size,
                              hipStream_t stream) {
    const float* latents = (const float*)d_in[0];
    const float* emb     = (const float*)d_in[1];
    float* out = (float*)d_out;
    float* partial = (float*)d_ws;

    fused_vq_kernel<<<FUSED_BLOCKS, 512, 0, stream>>>(latents, emb, out, partial);
    finalize_kernel<<<1, 512, 0, stream>>>(partial, out);
}